// Round 2
// baseline (185.873 us; speedup 1.0000x reference)
//
#include <hip/hip_runtime.h>

// Problem constants (from reference): B=4096, N_IN=64, N_OUT=64, M=4096.
#define BATCH 4096
#define NIN   64
#define NOUT  64
#define M_TOT (NIN * NOUT)

// ---------------------------------------------------------------------------
// Kernel 1: build WM from (aW, uW, tW). One thread per m = j*64 + k.
// Transposed layout for coalesced main-kernel loads:
//   WT[(j*3 + q)*64 + k] = row q of matrix (j,k)  (quad = (Rq0,Rq1,Rq2,tq))
// bottom row [0,0,0,1] implicit. 192 KiB in d_ws.
// ---------------------------------------------------------------------------
__global__ __launch_bounds__(256) void build_wm_kernel(
    const float* __restrict__ aW, const float* __restrict__ uW,
    const float* __restrict__ tW, float4* __restrict__ WT) {
  int m = blockIdx.x * 256 + threadIdx.x;
  if (m >= M_TOT) return;
  int j = m >> 6, k = m & 63;

  float a  = aW[m];
  float ux = 1.f / (1.f + expf(-uW[3 * m + 0]));
  float uy = 1.f / (1.f + expf(-uW[3 * m + 1]));
  float uz = 1.f / (1.f + expf(-uW[3 * m + 2]));
  float inv = 1.f / sqrtf(ux * ux + uy * uy + uz * uz);
  ux *= inv; uy *= inv; uz *= inv;

  float sa = sinf(a), ca = cosf(a);
  float xx = ux * ux, yy = uy * uy, zz = uz * uz;
  float xy = ux * uy, xz = ux * uz, yz = uy * uz;

  float R00 = ca * (1.f - xx) + xx;
  float R01 = -sa * uz + ca * (-xy) + xy;
  float R02 =  sa * uy + ca * (-xz) + xz;
  float R10 =  sa * uz + ca * (-xy) + xy;
  float R11 = ca * (1.f - yy) + yy;
  float R12 = -sa * ux + ca * (-yz) + yz;
  float R20 = -sa * uy + ca * (-xz) + xz;
  float R21 =  sa * ux + ca * (-yz) + yz;
  float R22 = ca * (1.f - zz) + zz;

  float t0 = tW[3 * m + 0], t1 = tW[3 * m + 1], t2 = tW[3 * m + 2];

  WT[(j * 3 + 0) * 64 + k] = make_float4(R00, R01, R02, t0);
  WT[(j * 3 + 1) * 64 + k] = make_float4(R10, R11, R12, t1);
  WT[(j * 3 + 2) * 64 + k] = make_float4(R20, R21, R22, t2);
}

// ---------------------------------------------------------------------------
// Kernel 2: chain product, 2-way split over j via associativity.
// Block = 256 threads = 4 waves; handles 2 batch rows:
//   wave {0,1} -> b = 2*blockIdx + {0,1}, j in [0,32)   (P0)
//   wave {2,3} -> b = 2*blockIdx + {0,1}, j in [32,64)  (P1)
// lane = k. I loads are wave-uniform -> readfirstlane + s_load (SGPR).
// W loads: lane-coalesced 1 KiB/instr. Combine O = P0 @ P1 through LDS.
// ---------------------------------------------------------------------------

// A (affine 4x4, rows w0..w2, bottom row [0,0,0,1]) applied to I rows r0..r3:
#define IMUL_ROW(Ar, r)                                              \
  Ar##0 = r.x * w0.x + r.y * w1.x + r.z * w2.x;                      \
  Ar##1 = r.x * w0.y + r.y * w1.y + r.z * w2.y;                      \
  Ar##2 = r.x * w0.z + r.y * w1.z + r.z * w2.z;                      \
  Ar##3 = r.x * w0.w + r.y * w1.w + r.z * w2.w + r.w;

#define CMUL_ROW(x)                                                            \
  {                                                                            \
    float t0 = c[x*4+0]*A00 + c[x*4+1]*A10 + c[x*4+2]*A20 + c[x*4+3]*A30;      \
    float t1 = c[x*4+0]*A01 + c[x*4+1]*A11 + c[x*4+2]*A21 + c[x*4+3]*A31;      \
    float t2 = c[x*4+0]*A02 + c[x*4+1]*A12 + c[x*4+2]*A22 + c[x*4+3]*A32;      \
    float t3 = c[x*4+0]*A03 + c[x*4+1]*A13 + c[x*4+2]*A23 + c[x*4+3]*A33;      \
    c[x*4+0] = t0; c[x*4+1] = t1; c[x*4+2] = t2; c[x*4+3] = t3;                \
  }

__global__ __launch_bounds__(256, 8) void chain_kernel(
    const float4* __restrict__ I4, const float4* __restrict__ WT,
    float4* __restrict__ O4) {
  const int lane = threadIdx.x & 63;
  const int wid  = threadIdx.x >> 6;   // 0..3
  const int half = wid >> 1;           // 0: j in [0,32), 1: j in [32,64)
  const int bloc = wid & 1;
  const int b    = __builtin_amdgcn_readfirstlane((int)blockIdx.x * 2 + bloc);

  const float4* __restrict__ Ib = I4 + (size_t)b * (NIN * 4) + half * (32 * 4);
  const float4* __restrict__ Wb = WT + (size_t)half * (32 * 3 * 64) + lane;

  float c[16];
#pragma unroll
  for (int i = 0; i < 16; i++) c[i] = (i == 0 || i == 5 || i == 10 || i == 15) ? 1.f : 0.f;

#pragma unroll 4
  for (int j = 0; j < 32; ++j) {
    float4 w0 = Wb[(3 * j + 0) * 64];
    float4 w1 = Wb[(3 * j + 1) * 64];
    float4 w2 = Wb[(3 * j + 2) * 64];
    float4 r0 = Ib[j * 4 + 0];
    float4 r1 = Ib[j * 4 + 1];
    float4 r2 = Ib[j * 4 + 2];
    float4 r3 = Ib[j * 4 + 3];

    float A00, A01, A02, A03, A10, A11, A12, A13;
    float A20, A21, A22, A23, A30, A31, A32, A33;
    IMUL_ROW(A0, r0)
    IMUL_ROW(A1, r1)
    IMUL_ROW(A2, r2)
    IMUL_ROW(A3, r3)

    CMUL_ROW(0)
    CMUL_ROW(1)
    CMUL_ROW(2)
    CMUL_ROW(3)
  }

  // combine: O = P0 @ P1
  __shared__ float P[2][64][17];  // padded stride 17 -> conflict-free
  if (half == 1) {
#pragma unroll
    for (int i = 0; i < 16; i++) P[bloc][lane][i] = c[i];
  }
  __syncthreads();
  if (half == 0) {
    float A00 = P[bloc][lane][0],  A01 = P[bloc][lane][1];
    float A02 = P[bloc][lane][2],  A03 = P[bloc][lane][3];
    float A10 = P[bloc][lane][4],  A11 = P[bloc][lane][5];
    float A12 = P[bloc][lane][6],  A13 = P[bloc][lane][7];
    float A20 = P[bloc][lane][8],  A21 = P[bloc][lane][9];
    float A22 = P[bloc][lane][10], A23 = P[bloc][lane][11];
    float A30 = P[bloc][lane][12], A31 = P[bloc][lane][13];
    float A32 = P[bloc][lane][14], A33 = P[bloc][lane][15];

    CMUL_ROW(0)
    CMUL_ROW(1)
    CMUL_ROW(2)
    CMUL_ROW(3)

    float4* o = O4 + ((size_t)b * NOUT + lane) * 4;
    o[0] = make_float4(c[0],  c[1],  c[2],  c[3]);
    o[1] = make_float4(c[4],  c[5],  c[6],  c[7]);
    o[2] = make_float4(c[8],  c[9],  c[10], c[11]);
    o[3] = make_float4(c[12], c[13], c[14], c[15]);
  }
}

extern "C" void kernel_launch(void* const* d_in, const int* in_sizes, int n_in,
                              void* d_out, int out_size, void* d_ws, size_t ws_size,
                              hipStream_t stream) {
  const float* I  = (const float*)d_in[0];
  const float* aW = (const float*)d_in[1];
  const float* uW = (const float*)d_in[2];
  const float* tW = (const float*)d_in[3];

  float4* WT = (float4*)d_ws;  // 192 KiB scratch for transposed WM

  build_wm_kernel<<<M_TOT / 256, 256, 0, stream>>>(aW, uW, tW, WT);
  chain_kernel<<<BATCH / 2, 256, 0, stream>>>((const float4*)I, WT, (float4*)d_out);
}

// Round 3
// 58.783 us; speedup vs baseline: 3.1620x; 3.1620x over previous
//
#include <hip/hip_runtime.h>

// Problem constants (from reference): B=4096, N_IN=64, N_OUT=64, M=4096.
#define BATCH 4096
#define NIN   64
#define NOUT  64
#define M_TOT (NIN * NOUT)

// ---------------------------------------------------------------------------
// Kernel 1: build WM from (aW, uW, tW). One thread per m = j*64 + k.
// Transposed layout for coalesced main-kernel loads:
//   WT[(j*3 + q)*64 + k] = row q of matrix (j,k)  (quad = (Rq0,Rq1,Rq2,tq))
// bottom row [0,0,0,1] implicit. 192 KiB in d_ws.
// ---------------------------------------------------------------------------
__global__ __launch_bounds__(256) void build_wm_kernel(
    const float* __restrict__ aW, const float* __restrict__ uW,
    const float* __restrict__ tW, float4* __restrict__ WT) {
  int m = blockIdx.x * 256 + threadIdx.x;
  if (m >= M_TOT) return;
  int j = m >> 6, k = m & 63;

  float a  = aW[m];
  float ux = 1.f / (1.f + expf(-uW[3 * m + 0]));
  float uy = 1.f / (1.f + expf(-uW[3 * m + 1]));
  float uz = 1.f / (1.f + expf(-uW[3 * m + 2]));
  float inv = 1.f / sqrtf(ux * ux + uy * uy + uz * uz);
  ux *= inv; uy *= inv; uz *= inv;

  float sa = sinf(a), ca = cosf(a);
  float xx = ux * ux, yy = uy * uy, zz = uz * uz;
  float xy = ux * uy, xz = ux * uz, yz = uy * uz;

  float R00 = ca * (1.f - xx) + xx;
  float R01 = -sa * uz + ca * (-xy) + xy;
  float R02 =  sa * uy + ca * (-xz) + xz;
  float R10 =  sa * uz + ca * (-xy) + xy;
  float R11 = ca * (1.f - yy) + yy;
  float R12 = -sa * ux + ca * (-yz) + yz;
  float R20 = -sa * uy + ca * (-xz) + xz;
  float R21 =  sa * ux + ca * (-yz) + yz;
  float R22 = ca * (1.f - zz) + zz;

  float t0 = tW[3 * m + 0], t1 = tW[3 * m + 1], t2 = tW[3 * m + 2];

  WT[(j * 3 + 0) * 64 + k] = make_float4(R00, R01, R02, t0);
  WT[(j * 3 + 1) * 64 + k] = make_float4(R10, R11, R12, t1);
  WT[(j * 3 + 2) * 64 + k] = make_float4(R20, R21, R22, t2);
}

// ---------------------------------------------------------------------------
// Kernel 2: chain product, 2-way split over j via associativity.
// Block = 256 threads = 4 waves, covering 2 batch rows:
//   wave wid: bloc = wid&1 (which b), half = wid>>1 (j range [0,32) / [32,64))
// lane = k. I loads via wave-uniform scalar pointer (s_load -> SGPRs).
// W loads lane-coalesced (1 KiB/instr), L2-resident. O = P0 @ P1 via LDS.
// NO register cap: round-2's __launch_bounds__(256,8) forced VGPR=32 and
// spilled ~200 MB to scratch (WRITE_SIZE 16->219 MB, VALUBusy 68->22%).
// ---------------------------------------------------------------------------

// A-row from I-row r and affine W rows w0..w2 (bottom row [0,0,0,1]):
#define IMUL_ROW(Ar, r)                                              \
  Ar##0 = r.x * w0.x + r.y * w1.x + r.z * w2.x;                      \
  Ar##1 = r.x * w0.y + r.y * w1.y + r.z * w2.y;                      \
  Ar##2 = r.x * w0.z + r.y * w1.z + r.z * w2.z;                      \
  Ar##3 = r.x * w0.w + r.y * w1.w + r.z * w2.w + r.w;

#define CMUL_ROW(x)                                                            \
  {                                                                            \
    float t0 = c[x*4+0]*A00 + c[x*4+1]*A10 + c[x*4+2]*A20 + c[x*4+3]*A30;      \
    float t1 = c[x*4+0]*A01 + c[x*4+1]*A11 + c[x*4+2]*A21 + c[x*4+3]*A31;      \
    float t2 = c[x*4+0]*A02 + c[x*4+1]*A12 + c[x*4+2]*A22 + c[x*4+3]*A32;      \
    float t3 = c[x*4+0]*A03 + c[x*4+1]*A13 + c[x*4+2]*A23 + c[x*4+3]*A33;      \
    c[x*4+0] = t0; c[x*4+1] = t1; c[x*4+2] = t2; c[x*4+3] = t3;                \
  }

#define LOAD_AND_IMUL(j)                                                       \
  float4 w0 = Wb[(3 * (j) + 0) * 64];                                          \
  float4 w1 = Wb[(3 * (j) + 1) * 64];                                          \
  float4 w2 = Wb[(3 * (j) + 2) * 64];                                          \
  float4 r0 = Ib[(j) * 4 + 0];                                                 \
  float4 r1 = Ib[(j) * 4 + 1];                                                 \
  float4 r2 = Ib[(j) * 4 + 2];                                                 \
  float4 r3 = Ib[(j) * 4 + 3];                                                 \
  float A00, A01, A02, A03, A10, A11, A12, A13;                                \
  float A20, A21, A22, A23, A30, A31, A32, A33;                                \
  IMUL_ROW(A0, r0)                                                             \
  IMUL_ROW(A1, r1)                                                             \
  IMUL_ROW(A2, r2)                                                             \
  IMUL_ROW(A3, r3)

__global__ __launch_bounds__(256) void chain_kernel(
    const float4* __restrict__ I4, const float4* __restrict__ WT,
    float4* __restrict__ O4) {
  const int lane = threadIdx.x & 63;
  const int wid  = threadIdx.x >> 6;   // 0..3
  const int half = wid >> 1;           // 0: j in [0,32), 1: j in [32,64)
  const int bloc = wid & 1;
  const int b    = (int)blockIdx.x * 2 + bloc;

  // wave-uniform scalar I base -> s_load, rows live in SGPRs
  const int ioff = __builtin_amdgcn_readfirstlane((b * NIN + half * 32) * 4);
  const float4* __restrict__ Ib = I4 + ioff;
  const float4* __restrict__ Wb = WT + (size_t)(half * 32 * 3) * 64 + lane;

  float c[16];
  {  // peeled j=0: c = A
    LOAD_AND_IMUL(0)
    c[0]  = A00; c[1]  = A01; c[2]  = A02; c[3]  = A03;
    c[4]  = A10; c[5]  = A11; c[6]  = A12; c[7]  = A13;
    c[8]  = A20; c[9]  = A21; c[10] = A22; c[11] = A23;
    c[12] = A30; c[13] = A31; c[14] = A32; c[15] = A33;
  }

#pragma unroll 2
  for (int j = 1; j < 32; ++j) {
    LOAD_AND_IMUL(j)
    CMUL_ROW(0)
    CMUL_ROW(1)
    CMUL_ROW(2)
    CMUL_ROW(3)
  }

  // combine: O = P0 @ P1
  __shared__ float P[2][64][17];  // padded stride 17 -> conflict-free
  if (half == 1) {
#pragma unroll
    for (int i = 0; i < 16; i++) P[bloc][lane][i] = c[i];
  }
  __syncthreads();
  if (half == 0) {
    float A00 = P[bloc][lane][0],  A01 = P[bloc][lane][1];
    float A02 = P[bloc][lane][2],  A03 = P[bloc][lane][3];
    float A10 = P[bloc][lane][4],  A11 = P[bloc][lane][5];
    float A12 = P[bloc][lane][6],  A13 = P[bloc][lane][7];
    float A20 = P[bloc][lane][8],  A21 = P[bloc][lane][9];
    float A22 = P[bloc][lane][10], A23 = P[bloc][lane][11];
    float A30 = P[bloc][lane][12], A31 = P[bloc][lane][13];
    float A32 = P[bloc][lane][14], A33 = P[bloc][lane][15];

    CMUL_ROW(0)
    CMUL_ROW(1)
    CMUL_ROW(2)
    CMUL_ROW(3)

    float4* o = O4 + ((size_t)b * NOUT + lane) * 4;
    o[0] = make_float4(c[0],  c[1],  c[2],  c[3]);
    o[1] = make_float4(c[4],  c[5],  c[6],  c[7]);
    o[2] = make_float4(c[8],  c[9],  c[10], c[11]);
    o[3] = make_float4(c[12], c[13], c[14], c[15]);
  }
}

extern "C" void kernel_launch(void* const* d_in, const int* in_sizes, int n_in,
                              void* d_out, int out_size, void* d_ws, size_t ws_size,
                              hipStream_t stream) {
  const float* I  = (const float*)d_in[0];
  const float* aW = (const float*)d_in[1];
  const float* uW = (const float*)d_in[2];
  const float* tW = (const float*)d_in[3];

  float4* WT = (float4*)d_ws;  // 192 KiB scratch for transposed WM

  build_wm_kernel<<<M_TOT / 256, 256, 0, stream>>>(aW, uW, tW, WT);
  chain_kernel<<<BATCH / 2, 256, 0, stream>>>((const float4*)I, WT, (float4*)d_out);
}